// Round 2
// baseline (301.303 us; speedup 1.0000x reference)
//
#include <hip/hip_runtime.h>

// qkv: (4, 8192, 3, 16, 64) f32 ; out: (4, 8192, 16, 64) f32
constexpr int   Bn    = 4;
constexpr int   Nn    = 8192;
constexpr int   Hn    = 16;
constexpr int   Dn    = 64;
constexpr int   QKV_N = 3 * Hn * Dn;                   // 3072
constexpr long long QKV_B = (long long)Nn * QKV_N;     // 25165824
constexpr int   OUT_N = Hn * Dn;                       // 1024
constexpr long long OUT_B = (long long)Nn * OUT_N;     // 8388608

// x + dpp_move(x): compiler fuses to a single v_add_f32_dpp (no LDS pipe).
template<int CTRL>
__device__ __forceinline__ float dpp_add(float x) {
  int mv = __builtin_amdgcn_update_dpp(0, __float_as_int(x), CTRL, 0xF, 0xF, true);
  return x + __int_as_float(mv);
}
// Sum across the 16-lane DPP row: xor1 (quad_perm 1,0,3,2 = 0xB1),
// xor2 (quad_perm 2,3,0,1 = 0x4E), then rotate by 4 and 8 within the row.
__device__ __forceinline__ float row16_sum(float x) {
  x = dpp_add<0xB1>(x);
  x = dpp_add<0x4E>(x);
  x = dpp_add<0x124>(x);   // row_ror:4
  x = dpp_add<0x128>(x);   // row_ror:8
  return x;
}

// Kernel 1: fused 3-branch dilated attention producing UNNORMALIZED out,
// plus f64 column sums via atomics (f32 per-lane partials).
// Work unit (b,h,j): group positions {j, j+2048, j+4096, j+6144}.
// One wave handles 4 consecutive j (sub = lane>>4), d split in quads (t16 = lane&15).
// One j-group per wave (no iteration loop) -> max TLP, min VGPR.
__global__ __launch_bounds__(256) void dil_main(const float* __restrict__ qkv,
                                                float* __restrict__ out,
                                                double* __restrict__ colsum) {
  const int tid = threadIdx.x;
  const int w   = tid >> 6;        // wave in block (0..3)
  const int l   = tid & 63;
  const int sub = l >> 4;          // which j within the wave's group of 4
  const int t16 = l & 15;          // which d-quad (d = t16*4 .. t16*4+3)
  const int bh  = blockIdx.y;      // 0..63
  const int b   = bh >> 4;
  const int h   = bh & 15;

  const int g = blockIdx.x * 4 + w;   // j-group 0..511
  const int j = g * 4 + sub;          // 0..2047

  const size_t qbase = (size_t)b * QKV_B + (size_t)h * Dn + (size_t)t16 * 4;
  const size_t obase = (size_t)b * OUT_B + (size_t)h * Dn + (size_t)t16 * 4;

  float q[4][4], k[4][4], v[4][4];
#pragma unroll
  for (int m = 0; m < 4; ++m) {
    const size_t o = qbase + (size_t)(m * 2048 + j) * QKV_N;
    float4 t;
    t = *(const float4*)(qkv + o);
    q[m][0] = t.x; q[m][1] = t.y; q[m][2] = t.z; q[m][3] = t.w;
    t = *(const float4*)(qkv + o + 1024);
    k[m][0] = t.x; k[m][1] = t.y; k[m][2] = t.z; k[m][3] = t.w;
    t = *(const float4*)(qkv + o + 2048);
    v[m][0] = t.x; v[m][1] = t.y; v[m][2] = t.z; v[m][3] = t.w;
  }

  // 4x4 score matrix: per-lane partial over d-quad, then DPP row reduce.
  float S[4][4];
#pragma unroll
  for (int m = 0; m < 4; ++m)
#pragma unroll
    for (int m2 = 0; m2 < 4; ++m2) {
      float s = q[m][0] * k[m2][0] + q[m][1] * k[m2][1] +
                q[m][2] * k[m2][2] + q[m][3] * k[m2][3];
      S[m][m2] = row16_sum(s) * 0.125f;   // * 1/sqrt(64)
    }

  float acc[4][4];

  // ---- branch 1 (r=1): softmax over all 4 keys, every position ----
#pragma unroll
  for (int m = 0; m < 4; ++m) {
    float mx = fmaxf(fmaxf(S[m][0], S[m][1]), fmaxf(S[m][2], S[m][3]));
    float e0 = __expf(S[m][0] - mx);
    float e1 = __expf(S[m][1] - mx);
    float e2 = __expf(S[m][2] - mx);
    float e3 = __expf(S[m][3] - mx);
    float inv = 1.0f / (e0 + e1 + e2 + e3);
    e0 *= inv; e1 *= inv; e2 *= inv; e3 *= inv;
#pragma unroll
    for (int c = 0; c < 4; ++c)
      acc[m][c] = e0 * v[0][c] + e1 * v[1][c] + e2 * v[2][c] + e3 * v[3][c];
  }

  // ---- branch 2 (r=2): applies iff j even  <=>  sub even ----
  if ((sub & 1) == 0) {
#pragma unroll
    for (int m = 0; m < 4; ++m) {
      const int a  = m & 1;
      const int b2 = a + 2;
      float sa = S[m][a], sb = S[m][b2];
      float mx = fmaxf(sa, sb);
      float ea = __expf(sa - mx);
      float eb = __expf(sb - mx);
      float inv = 1.0f / (ea + eb);
      ea *= inv; eb *= inv;
#pragma unroll
      for (int c = 0; c < 4; ++c)
        acc[m][c] += ea * v[a][c] + eb * v[b2][c];
    }
  }

  // ---- branch 3 (r=4): applies iff j % 4 == 0  <=>  sub == 0 ----
  if (sub == 0) {
#pragma unroll
    for (int m = 0; m < 4; ++m)
#pragma unroll
      for (int c = 0; c < 4; ++c)
        acc[m][c] += v[m][c];
  }

  // ---- store unnormalized out ----
#pragma unroll
  for (int m = 0; m < 4; ++m) {
    float4 st = make_float4(acc[m][0], acc[m][1], acc[m][2], acc[m][3]);
    *(float4*)(out + obase + (size_t)(m * 2048 + j) * OUT_N) = st;
  }

  // ---- column-sum partials: f32 per lane, reduce across the 4 subs,
  //      then one f64 atomic per (d) from lanes 0..15 only ----
  float cs[4];
#pragma unroll
  for (int c = 0; c < 4; ++c)
    cs[c] = acc[0][c] + acc[1][c] + acc[2][c] + acc[3][c];
#pragma unroll
  for (int c = 0; c < 4; ++c) {
    cs[c] += __shfl_xor(cs[c], 32, 64);
    cs[c] += __shfl_xor(cs[c], 16, 64);
  }
  if (sub == 0) {
    double* cp = colsum + (size_t)bh * Dn + (size_t)t16 * 4;
    atomicAdd(cp + 0, (double)cs[0]);
    atomicAdd(cp + 1, (double)cs[1]);
    atomicAdd(cp + 2, (double)cs[2]);
    atomicAdd(cp + 3, (double)cs[3]);
  }
}

// Kernel 2: reciprocal table (4096 entries)
__global__ __launch_bounds__(256) void dil_recip(const double* __restrict__ colsum,
                                                 float* __restrict__ recip) {
  const int i = blockIdx.x * 256 + threadIdx.x;
  if (i < Bn * Hn * Dn)
    recip[i] = (float)(1.0 / colsum[i]);
}

// Kernel 3: out *= recip (broadcast over n)
__global__ __launch_bounds__(256) void dil_scale(float* __restrict__ out,
                                                 const float* __restrict__ recip) {
  const long long f = (long long)blockIdx.x * 256 + threadIdx.x;  // float4 index
  const int d4 = (int)(f & 15);
  const int h  = (int)((f >> 4) & 15);
  const int b  = (int)(f >> 21);
  const float4 r = ((const float4*)recip)[(b * 16 + h) * 16 + d4];
  float4 o = ((const float4*)out)[f];
  o.x *= r.x; o.y *= r.y; o.z *= r.z; o.w *= r.w;
  ((float4*)out)[f] = o;
}

extern "C" void kernel_launch(void* const* d_in, const int* in_sizes, int n_in,
                              void* d_out, int out_size, void* d_ws, size_t ws_size,
                              hipStream_t stream) {
  const float* qkv = (const float*)d_in[0];
  float* out = (float*)d_out;

  double* colsum = (double*)d_ws;                        // 4096 doubles = 32 KB
  float*  recip  = (float*)((char*)d_ws + 32768);        // 4096 floats  = 16 KB

  hipMemsetAsync(d_ws, 0, 4096 * sizeof(double), stream);

  dim3 grid1(128, 64);   // x: j-group chunks (4 groups/block), y: (b,h)
  dil_main<<<grid1, 256, 0, stream>>>(qkv, out, colsum);

  dil_recip<<<16, 256, 0, stream>>>(colsum, recip);

  const long long nf4 = (long long)Bn * Nn * Hn * Dn / 4;   // 8388608
  dil_scale<<<(int)(nf4 / 256), 256, 0, stream>>>(out, recip);
}

// Round 3
// 178.993 us; speedup vs baseline: 1.6833x; 1.6833x over previous
//
#include <hip/hip_runtime.h>

// qkv: (4, 8192, 3, 16, 64) f32 ; out: (4, 8192, 16, 64) f32
constexpr int   Bn    = 4;
constexpr int   Nn    = 8192;
constexpr int   Hn    = 16;
constexpr int   Dn    = 64;
constexpr int   ROW   = 3 * Hn * Dn;                   // 3072 floats = 12 KB
constexpr long long QKV_B = (long long)Nn * ROW;       // 25165824
constexpr int   OUT_N = Hn * Dn;                       // 1024
constexpr long long OUT_B = (long long)Nn * OUT_N;     // 8388608

// x + dpp_move(x): fuses to a single v_add_f32_dpp (no LDS pipe).
template<int CTRL>
__device__ __forceinline__ float dpp_add(float x) {
  int mv = __builtin_amdgcn_update_dpp(0, __float_as_int(x), CTRL, 0xF, 0xF, true);
  return x + __int_as_float(mv);
}
// Sum across a 16-lane DPP row: quad_perm xor1 (0xB1), xor2 (0x4E), row_ror:4, row_ror:8.
__device__ __forceinline__ float row16_sum(float x) {
  x = dpp_add<0xB1>(x);
  x = dpp_add<0x4E>(x);
  x = dpp_add<0x124>(x);
  x = dpp_add<0x128>(x);
  return x;
}

// Block = one (b, j-lane) covering ALL 16 heads; 4 j's per block sequentially.
// Rows {j, j+2048, j+4096, j+6144} are read as CONTIGUOUS 12 KB streams:
//   q+k (8 KB/row) staged in LDS with stride-1 float4 loads, v direct to regs.
// Thread tid = h*16 + t16: head h, d-quad t16 (lanes 0-15 of a wave share h).
__global__ __launch_bounds__(256) void dil_main(const float* __restrict__ qkv,
                                                float* __restrict__ out,
                                                double* __restrict__ colsum,
                                                int repMask) {
  __shared__ float lds[4][2048];   // [m][ q:0..1023 | k:1024..2047 ]
  const int tid  = threadIdx.x;
  const int h    = tid >> 4;
  const int t16  = tid & 15;
  const int bid  = blockIdx.x;     // 0..2047
  const int b    = bid >> 9;
  const int jbase= bid & 511;

  const float* qb = qkv + (size_t)b * QKV_B;
  float*       ob = out + (size_t)b * OUT_B;

  float cs[4] = {0.f, 0.f, 0.f, 0.f};

  for (int it = 0; it < 4; ++it) {
    const int j = jbase + it * 512;
    if (it) __syncthreads();   // protect LDS reuse

    // ---- stage q+k: flat over [4 rows][first 2048 floats], stride-1 per wave ----
#pragma unroll
    for (int c = 0; c < 8; ++c) {
      const int f   = c * 1024 + tid * 4;
      const int m   = f >> 11;
      const int off = f & 2047;
      const float4 t = *(const float4*)(qb + (size_t)(m * 2048 + j) * ROW + off);
      *(float4*)(&lds[m][off]) = t;
    }

    // ---- v direct to registers at this thread's (h, d-quad) ----
    float v[4][4];
#pragma unroll
    for (int m = 0; m < 4; ++m) {
      const float4 t = *(const float4*)(qb + (size_t)(m * 2048 + j) * ROW +
                                        2048 + h * 64 + t16 * 4);
      v[m][0] = t.x; v[m][1] = t.y; v[m][2] = t.z; v[m][3] = t.w;
    }

    __syncthreads();

    // ---- q,k fragments from LDS ----
    float q[4][4], k[4][4];
#pragma unroll
    for (int m = 0; m < 4; ++m) {
      float4 t = *(const float4*)(&lds[m][h * 64 + t16 * 4]);
      q[m][0] = t.x; q[m][1] = t.y; q[m][2] = t.z; q[m][3] = t.w;
      t = *(const float4*)(&lds[m][1024 + h * 64 + t16 * 4]);
      k[m][0] = t.x; k[m][1] = t.y; k[m][2] = t.z; k[m][3] = t.w;
    }

    // ---- 4x4 scores: per-lane d-quad partial, DPP 16-lane reduce ----
    float S[4][4];
#pragma unroll
    for (int m = 0; m < 4; ++m)
#pragma unroll
      for (int m2 = 0; m2 < 4; ++m2) {
        float s = q[m][0] * k[m2][0] + q[m][1] * k[m2][1] +
                  q[m][2] * k[m2][2] + q[m][3] * k[m2][3];
        S[m][m2] = row16_sum(s) * 0.125f;   // 1/sqrt(64)
      }

    float acc[4][4];

    // ---- branch 1 (r=1): softmax over 4 keys, every position ----
#pragma unroll
    for (int m = 0; m < 4; ++m) {
      float mx = fmaxf(fmaxf(S[m][0], S[m][1]), fmaxf(S[m][2], S[m][3]));
      float e0 = __expf(S[m][0] - mx);
      float e1 = __expf(S[m][1] - mx);
      float e2 = __expf(S[m][2] - mx);
      float e3 = __expf(S[m][3] - mx);
      float inv = 1.0f / (e0 + e1 + e2 + e3);
      e0 *= inv; e1 *= inv; e2 *= inv; e3 *= inv;
#pragma unroll
      for (int c = 0; c < 4; ++c)
        acc[m][c] = e0 * v[0][c] + e1 * v[1][c] + e2 * v[2][c] + e3 * v[3][c];
    }

    // ---- branch 2 (r=2): iff j even (block-uniform) ----
    if ((j & 1) == 0) {
#pragma unroll
      for (int m = 0; m < 4; ++m) {
        const int a  = m & 1;
        const int b2 = a + 2;
        float sa = S[m][a], sb = S[m][b2];
        float mx = fmaxf(sa, sb);
        float ea = __expf(sa - mx);
        float eb = __expf(sb - mx);
        float inv = 1.0f / (ea + eb);
        ea *= inv; eb *= inv;
#pragma unroll
        for (int c = 0; c < 4; ++c)
          acc[m][c] += ea * v[a][c] + eb * v[b2][c];
      }
    }

    // ---- branch 3 (r=4): iff j % 4 == 0 (block-uniform) ----
    if ((j & 3) == 0) {
#pragma unroll
      for (int m = 0; m < 4; ++m)
#pragma unroll
        for (int c = 0; c < 4; ++c)
          acc[m][c] += v[m][c];
    }

    // ---- store unnormalized out; accumulate colsum partial in regs ----
#pragma unroll
    for (int m = 0; m < 4; ++m) {
      float4 st = make_float4(acc[m][0], acc[m][1], acc[m][2], acc[m][3]);
      *(float4*)(ob + (size_t)(m * 2048 + j) * OUT_N + h * 64 + t16 * 4) = st;
      cs[0] += acc[m][0]; cs[1] += acc[m][1];
      cs[2] += acc[m][2]; cs[3] += acc[m][3];
    }
  }

  // ---- one f64 atomic set per thread, into a replicated slot ----
  double* cp = colsum + (size_t)(bid & repMask) * 4096 +
               ((size_t)b * 16 + h) * 64 + t16 * 4;
  atomicAdd(cp + 0, (double)cs[0]);
  atomicAdd(cp + 1, (double)cs[1]);
  atomicAdd(cp + 2, (double)cs[2]);
  atomicAdd(cp + 3, (double)cs[3]);
}

// Kernel 2: reduce replicas + reciprocal table (4096 entries)
__global__ __launch_bounds__(256) void dil_recip(const double* __restrict__ colsum,
                                                 float* __restrict__ recip, int rep) {
  const int i = blockIdx.x * 256 + threadIdx.x;
  if (i < Bn * Hn * Dn) {
    double s = 0.0;
    for (int r = 0; r < rep; ++r) s += colsum[(size_t)r * 4096 + i];
    recip[i] = (float)(1.0 / s);
  }
}

// Kernel 3: out *= recip (broadcast over n)
__global__ __launch_bounds__(256) void dil_scale(float* __restrict__ out,
                                                 const float* __restrict__ recip) {
  const long long f = (long long)blockIdx.x * 256 + threadIdx.x;  // float4 index
  const int d4 = (int)(f & 15);
  const int h  = (int)((f >> 4) & 15);
  const int b  = (int)(f >> 21);
  const float4 r = ((const float4*)recip)[(b * 16 + h) * 16 + d4];
  float4 o = ((const float4*)out)[f];
  o.x *= r.x; o.y *= r.y; o.z *= r.z; o.w *= r.w;
  ((float4*)out)[f] = o;
}

extern "C" void kernel_launch(void* const* d_in, const int* in_sizes, int n_in,
                              void* d_out, int out_size, void* d_ws, size_t ws_size,
                              hipStream_t stream) {
  const float* qkv = (const float*)d_in[0];
  float* out = (float*)d_out;

  int rep = 32;
  while (rep > 1 &&
         (size_t)rep * 4096 * sizeof(double) + 4096 * sizeof(float) > ws_size)
    rep >>= 1;

  double* colsum = (double*)d_ws;
  float*  recip  = (float*)((char*)d_ws + (size_t)rep * 4096 * sizeof(double));

  hipMemsetAsync(d_ws, 0, (size_t)rep * 4096 * sizeof(double), stream);

  dil_main<<<2048, 256, 0, stream>>>(qkv, out, colsum, rep - 1);

  dil_recip<<<16, 256, 0, stream>>>(colsum, recip, rep);

  const long long nf4 = (long long)Bn * Nn * Hn * Dn / 4;   // 8388608
  dil_scale<<<(int)(nf4 / 256), 256, 0, stream>>>(out, recip);
}